// Round 2
// baseline (166.986 us; speedup 1.0000x reference)
//
#include <hip/hip_runtime.h>
#include <hip/hip_bf16.h>

// GATLayer: x[8,1024,128], e[8,1024,1024], H=8 dh=16, CLIP=10, FF=512.
// Plan: 5 kernels: qkv-proj GEMM -> fused attention (all heads per block,
// swapped-QK^T 32x32x16 bf16 MFMA, fixed-max softmax exploiting tanh clip)
// -> Wo+res1 -> FFN1(relu) -> FFN2+res2.

typedef __attribute__((ext_vector_type(4)))  float  f32x4;
typedef __attribute__((ext_vector_type(16))) float  f32x16;
typedef __attribute__((ext_vector_type(8)))  __bf16 bf8v;

#define DEV static __device__ __forceinline__

DEV ushort f2bf(float f) {
  __hip_bfloat16 h = __float2bfloat16(f);
  return __builtin_bit_cast(ushort, h);
}

DEV uint pk2(float a, float b) {
  return (uint)f2bf(a) | ((uint)f2bf(b) << 16);
}

DEV f32x16 zero16() {
  f32x16 z;
#pragma unroll
  for (int i = 0; i < 16; ++i) z[i] = 0.0f;
  return z;
}

union PU {
  uint u[4];
  bf8v v;
};

// ---------------- generic 64x64 GEMM tile (bf16 MFMA, f32 accum) -----------
// A: row-major [M x K] (f32 or bf16 per ABF). B: row-major f32 [K x ldb].
// 256 threads = 4 waves; wave w owns 32x32 tile at (w&1)*32, (w>>1)*32.
template <bool ABF>
DEV f32x16 gemm_block(const void* Ap, const float* Bp, int K, int ldb,
                      int m0, int n0, ushort (*As)[136], ushort (*Bs)[136]) {
  const int t = threadIdx.x;
  const int lane = t & 63, wave = t >> 6;
  const int lq = lane & 31, hi = lane >> 5;
  const int mrow = (wave & 1) * 32, ncol = (wave >> 1) * 32;
  f32x16 acc = zero16();
  for (int k0 = 0; k0 < K; k0 += 128) {
    __syncthreads();
    if constexpr (ABF) {
      const ushort* A = (const ushort*)Ap;
#pragma unroll
      for (int j = 0; j < 4; ++j) {
        int idx = t + 256 * j;          // 64 rows x 16 chunks of 8 bf16
        int m = idx >> 4, kv = idx & 15;
        uint4 v = *(const uint4*)(A + (size_t)(m0 + m) * K + k0 + kv * 8);
        *(uint4*)&As[m][kv * 8] = v;
      }
    } else {
      const float* A = (const float*)Ap;
#pragma unroll
      for (int j = 0; j < 8; ++j) {
        int idx = t + 256 * j;          // 64 rows x 32 float4
        int m = idx >> 5, kv = idx & 31;
        f32x4 v = *(const f32x4*)(A + (size_t)(m0 + m) * K + k0 + kv * 4);
        ushort4 uv = make_ushort4(f2bf(v.x), f2bf(v.y), f2bf(v.z), f2bf(v.w));
        *(ushort4*)&As[m][kv * 4] = uv;
      }
    }
    // stage B transposed: Bs[n][k] = B[k0+k][n0+n]
#pragma unroll
    for (int j = 0; j < 8; ++j) {
      int idx = t + 256 * j;            // 128 k-rows x 16 float4
      int k = idx >> 4, nv = idx & 15;
      f32x4 v = *(const f32x4*)(Bp + (size_t)(k0 + k) * ldb + n0 + nv * 4);
      Bs[nv * 4 + 0][k] = f2bf(v.x);
      Bs[nv * 4 + 1][k] = f2bf(v.y);
      Bs[nv * 4 + 2][k] = f2bf(v.z);
      Bs[nv * 4 + 3][k] = f2bf(v.w);
    }
    __syncthreads();
#pragma unroll
    for (int c = 0; c < 8; ++c) {
      bf8v af = *(const bf8v*)&As[mrow + lq][c * 16 + hi * 8];
      bf8v bf = *(const bf8v*)&Bs[ncol + lq][c * 16 + hi * 8];
      acc = __builtin_amdgcn_mfma_f32_32x32x16_bf16(af, bf, acc, 0, 0, 0);
    }
  }
  return acc;
}

// C-layout row for reg r: (r&3) + 8*(r>>2) + 4*hi ; col = lane&31.

// ---------------- kernel 1: QKV projection --------------------------------
// Writes Q,K as [B,H,N,16] bf16; V transposed [B,H,16,N] bf16.
__global__ __launch_bounds__(256) void proj_kernel(
    const float* __restrict__ x, const float* __restrict__ Wq,
    const float* __restrict__ Wk, const float* __restrict__ Wv,
    ushort* __restrict__ Qb, ushort* __restrict__ Kb, ushort* __restrict__ Vt) {
  __shared__ ushort As[64][136], Bs[64][136];
  const int mb = blockIdx.x, nb = blockIdx.y;
  const int proj = nb >> 1;
  const float* W = proj == 0 ? Wq : (proj == 1 ? Wk : Wv);
  const int n0 = (nb & 1) * 64;
  f32x16 acc = gemm_block<false>(x, W, 128, 128, mb * 64, n0, As, Bs);
  const int lane = threadIdx.x & 63, wave = threadIdx.x >> 6;
  const int lq = lane & 31, hi = lane >> 5;
  const int mbase = mb * 64 + (wave & 1) * 32;
  const int nloc = n0 + (wave >> 1) * 32 + lq;   // 0..127 within this proj
  const int h = nloc >> 4, d = nloc & 15;
#pragma unroll
  for (int r = 0; r < 16; ++r) {
    int m = mbase + (r & 3) + 8 * (r >> 2) + 4 * hi;   // 0..8191
    int b = m >> 10, ns = m & 1023;
    ushort val = f2bf(acc[r]);
    if (proj < 2) {
      ushort* dst = proj ? Kb : Qb;
      dst[((size_t)(b * 8 + h) * 1024 + ns) * 16 + d] = val;
    } else {
      Vt[((size_t)(b * 8 + h) * 16 + d) * 1024 + ns] = val;
    }
  }
}

// ---------------- kernel 2: fused attention -------------------------------
// grid = B*32 blocks (one per (b, 32-row q-tile)); 512 thr = 8 waves = 8 heads.
// Swapped QK^T: S^T = mfma(K, Q) so lane owns q = lane&31; softmax uses the
// tanh clip (t in [-10,10]) -> fixed max offset 10, no online rescale.
__global__ __launch_bounds__(512) void attn_kernel(
    const ushort* __restrict__ Qb, const ushort* __restrict__ Kb,
    const ushort* __restrict__ Vt, const float* __restrict__ e,
    ushort* __restrict__ AO) {
  const int b = blockIdx.x >> 5, qt = blockIdx.x & 31;
  const int h = threadIdx.x >> 6, lane = threadIdx.x & 63;
  const int lq = lane & 31, hi = lane >> 5;
  const int q0 = qt * 32;
  const ushort* Qh = Qb + (size_t)(b * 8 + h) * (1024 * 16);
  const ushort* Kh = Kb + (size_t)(b * 8 + h) * (1024 * 16);
  const ushort* Vh = Vt + (size_t)(b * 8 + h) * (16 * 1024);
  const float* erow = e + ((size_t)b * 1024 + q0 + lq) * 1024;

  const bf8v qf = *(const bf8v*)(Qh + (q0 + lq) * 16 + hi * 8);
  f32x16 acc = zero16();
  float ssum = 0.0f;
  const float C2 = 2.8853900817779268f;    // 2*log2(e)
  const float C1 = -28.853900817779268f;   // -20*log2(e)

  for (int mt = 0; mt < 32; ++mt) {
    const int mbase = mt * 32;
    bf8v kf = *(const bf8v*)(Kh + (mbase + lq) * 16 + hi * 8);
    f32x16 s = __builtin_amdgcn_mfma_f32_32x32x16_bf16(kf, qf, zero16(), 0, 0, 0);
    // e[b][q][m] for this lane's 16 m's: groups of 4 consecutive m
    f32x4 ev[4];
#pragma unroll
    for (int g = 0; g < 4; ++g)
      ev[g] = *(const f32x4*)(erow + mbase + 4 * hi + 8 * g);
    float p[16];
#pragma unroll
    for (int r = 0; r < 16; ++r) {
      float y = s[r] * 0.25f + ev[r >> 2][r & 3];
      // p = exp(10*tanh(y) - 10) = exp2(C1 / (1 + exp2(C2*y)))
      float z = __builtin_amdgcn_exp2f(C2 * y);
      float pp = __builtin_amdgcn_exp2f(C1 * __builtin_amdgcn_rcpf(1.0f + z));
      p[r] = pp;
      ssum += pp;
    }
    // pack P to bf16 words; exchange halves with partner lane (lane^32)
    uint w[8], pw[8];
#pragma unroll
    for (int j = 0; j < 8; ++j) w[j] = pk2(p[2 * j], p[2 * j + 1]);
#pragma unroll
    for (int j = 0; j < 8; ++j) pw[j] = (uint)__shfl_xor((int)w[j], 32);
    // A-frag (rows=q, k = m within 16-chunk):
    // chunk0 (m 0..15): hi0 {w0,w1,pw0,pw1} ; hi1 {pw2,pw3,w2,w3}
    // chunk1 (m16..31): hi0 {w4,w5,pw4,pw5} ; hi1 {pw6,pw7,w6,w7}
    PU a0, a1;
    a0.u[0] = hi ? pw[2] : w[0];
    a0.u[1] = hi ? pw[3] : w[1];
    a0.u[2] = hi ? w[2] : pw[0];
    a0.u[3] = hi ? w[3] : pw[1];
    a1.u[0] = hi ? pw[6] : w[4];
    a1.u[1] = hi ? pw[7] : w[5];
    a1.u[2] = hi ? w[6] : pw[4];
    a1.u[3] = hi ? w[7] : pw[5];
    // V B-frags: col = d (lanes 0..15 valid), k = m; Vt rows are contiguous
    PU v0, v1;
#pragma unroll
    for (int j = 0; j < 4; ++j) { v0.u[j] = 0; v1.u[j] = 0; }
    if (lq < 16) {
      v0.v = *(const bf8v*)(Vh + lq * 1024 + mbase + hi * 8);
      v1.v = *(const bf8v*)(Vh + lq * 1024 + mbase + 16 + hi * 8);
    }
    acc = __builtin_amdgcn_mfma_f32_32x32x16_bf16(a0.v, v0.v, acc, 0, 0, 0);
    acc = __builtin_amdgcn_mfma_f32_32x32x16_bf16(a1.v, v1.v, acc, 0, 0, 0);
  }
  // full row-sum: this lane has half the m's, partner has the other half
  float tot = ssum + __shfl_xor(ssum, 32);
  // normalize and store: acc reg r -> row q_r, col d = lq (d<16 valid)
#pragma unroll
  for (int r = 0; r < 16; ++r) {
    int qr = (r & 3) + 8 * (r >> 2) + 4 * hi;
    float dn = __shfl(tot, qr);   // denom lives at lane qr (both halves equal)
    if (lq < 16) {
      float o = acc[r] * __builtin_amdgcn_rcpf(dn);
      AO[((size_t)(b * 1024) + q0 + qr) * 128 + h * 16 + lq] = f2bf(o);
    }
  }
}

// ---------------- kernel 3: Wo GEMM + residual 1 --------------------------
__global__ __launch_bounds__(256) void wo_res_kernel(
    const ushort* __restrict__ AO, const float* __restrict__ Wo,
    const float* __restrict__ x, const float* __restrict__ alpha1,
    float* __restrict__ X1, ushort* __restrict__ X1b) {
  __shared__ ushort As[64][136], Bs[64][136];
  const int mb = blockIdx.x, nb = blockIdx.y;
  f32x16 acc = gemm_block<true>(AO, Wo, 128, 128, mb * 64, nb * 64, As, Bs);
  const float a1 = *alpha1;
  const int lane = threadIdx.x & 63, wave = threadIdx.x >> 6;
  const int lq = lane & 31, hi = lane >> 5;
  const int mbase = mb * 64 + (wave & 1) * 32;
  const int n = nb * 64 + (wave >> 1) * 32 + lq;
#pragma unroll
  for (int r = 0; r < 16; ++r) {
    int m = mbase + (r & 3) + 8 * (r >> 2) + 4 * hi;
    float v = x[(size_t)m * 128 + n] + a1 * acc[r];
    X1[(size_t)m * 128 + n] = v;
    X1b[(size_t)m * 128 + n] = f2bf(v);
  }
}

// ---------------- kernel 4: FFN layer 1 (relu) ----------------------------
__global__ __launch_bounds__(256) void ffn1_kernel(
    const ushort* __restrict__ X1b, const float* __restrict__ W1,
    const float* __restrict__ b1, ushort* __restrict__ Hb) {
  __shared__ ushort As[64][136], Bs[64][136];
  const int mb = blockIdx.x, nb = blockIdx.y;
  f32x16 acc = gemm_block<true>(X1b, W1, 128, 512, mb * 64, nb * 64, As, Bs);
  const int lane = threadIdx.x & 63, wave = threadIdx.x >> 6;
  const int lq = lane & 31, hi = lane >> 5;
  const int mbase = mb * 64 + (wave & 1) * 32;
  const int n = nb * 64 + (wave >> 1) * 32 + lq;
  const float bias = b1[n];
#pragma unroll
  for (int r = 0; r < 16; ++r) {
    int m = mbase + (r & 3) + 8 * (r >> 2) + 4 * hi;
    float v = fmaxf(acc[r] + bias, 0.0f);
    Hb[(size_t)m * 512 + n] = f2bf(v);
  }
}

// ---------------- kernel 5: FFN layer 2 + residual 2 ----------------------
__global__ __launch_bounds__(256) void ffn2_kernel(
    const ushort* __restrict__ Hb, const float* __restrict__ W2,
    const float* __restrict__ b2, const float* __restrict__ X1,
    const float* __restrict__ alpha2, float* __restrict__ out) {
  __shared__ ushort As[64][136], Bs[64][136];
  const int mb = blockIdx.x, nb = blockIdx.y;
  f32x16 acc = gemm_block<true>(Hb, W2, 512, 128, mb * 64, nb * 64, As, Bs);
  const float a2 = *alpha2;
  const int lane = threadIdx.x & 63, wave = threadIdx.x >> 6;
  const int lq = lane & 31, hi = lane >> 5;
  const int mbase = mb * 64 + (wave & 1) * 32;
  const int n = nb * 64 + (wave >> 1) * 32 + lq;
  const float bias = b2[n];
#pragma unroll
  for (int r = 0; r < 16; ++r) {
    int m = mbase + (r & 3) + 8 * (r >> 2) + 4 * hi;
    float v = X1[(size_t)m * 128 + n] + a2 * (acc[r] + bias);
    out[(size_t)m * 128 + n] = v;
  }
}

// ---------------- launcher -------------------------------------------------
extern "C" void kernel_launch(void* const* d_in, const int* in_sizes, int n_in,
                              void* d_out, int out_size, void* d_ws, size_t ws_size,
                              hipStream_t stream) {
  (void)in_sizes; (void)n_in; (void)out_size; (void)ws_size;
  const float* x  = (const float*)d_in[0];
  const float* e  = (const float*)d_in[1];
  const float* Wq = (const float*)d_in[2];
  const float* Wk = (const float*)d_in[3];
  const float* Wv = (const float*)d_in[4];
  const float* Wo = (const float*)d_in[5];
  const float* W1 = (const float*)d_in[6];
  const float* b1 = (const float*)d_in[7];
  const float* W2 = (const float*)d_in[8];
  const float* b2 = (const float*)d_in[9];
  const float* a1 = (const float*)d_in[10];
  const float* a2 = (const float*)d_in[11];
  float* out = (float*)d_out;

  char* ws = (char*)d_ws;
  ushort* Qb  = (ushort*)(ws);                    // 2 MB [B,H,N,16] bf16
  ushort* Kb  = (ushort*)(ws + (2ull << 20));     // 2 MB
  ushort* Vt  = (ushort*)(ws + (4ull << 20));     // 2 MB [B,H,16,N] bf16
  ushort* AO  = (ushort*)(ws + (6ull << 20));     // 2 MB [8192,128] bf16
  float*  X1  = (float*) (ws + (8ull << 20));     // 4 MB f32
  ushort* X1b = (ushort*)(ws + (12ull << 20));    // 2 MB bf16
  ushort* Hb  = (ushort*)(ws + (14ull << 20));    // 8 MB [8192,512] bf16

  proj_kernel<<<dim3(128, 6), 256, 0, stream>>>(x, Wq, Wk, Wv, Qb, Kb, Vt);
  attn_kernel<<<dim3(256), 512, 0, stream>>>(Qb, Kb, Vt, e, AO);
  wo_res_kernel<<<dim3(128, 2), 256, 0, stream>>>(AO, Wo, x, a1, X1, X1b);
  ffn1_kernel<<<dim3(128, 8), 256, 0, stream>>>(X1b, W1, b1, Hb);
  ffn2_kernel<<<dim3(128, 2), 256, 0, stream>>>(Hb, W2, b2, X1, a2, out);
}